// Round 5
// baseline (28714.227 us; speedup 1.0000x reference)
//
#include <hip/hip_runtime.h>

#define KNBR 32
#define NCELL 4096      // 16^3 Morton cells
#define FT 512          // fps threads (512 is the config the allocator treats well: R2 gave 120 VGPRs)
#define FP 40           // points per fps thread
#define FPQ (FP / 4)    // float4 groups per thread
#define FCAP (FT * FP)  // padded point capacity (20480)
#define NW (FT / 64)    // waves

// Reference-matching squared distance: ((dx*dx + dy*dy) + dz*dz), no FMA contraction.
__device__ __forceinline__ float sq_dist_nofma(float px, float py, float pz,
                                               float cx, float cy, float cz) {
    float dx = __fsub_rn(px, cx);
    float dy = __fsub_rn(py, cy);
    float dz = __fsub_rn(pz, cz);
    return __fadd_rn(__fadd_rn(__fmul_rn(dx, dx), __fmul_rn(dy, dy)), __fmul_rn(dz, dz));
}

__device__ __forceinline__ unsigned spread4(unsigned v) {
    return (v & 1u) | ((v & 2u) << 2) | ((v & 4u) << 4) | ((v & 8u) << 6);
}

// K1: AoS -> SoA + norms + Morton cell id + within-cell rank (counting-sort pass 1)
__global__ void prep_kernel(const float* __restrict__ coord, int N,
                            float* __restrict__ sx, float* __restrict__ sy,
                            float* __restrict__ sz, float* __restrict__ sn,
                            int* __restrict__ cell, int* __restrict__ rank,
                            int* __restrict__ hist) {
    int i = blockIdx.x * blockDim.x + threadIdx.x;
    if (i < N) {
        float x = coord[3 * i + 0];
        float y = coord[3 * i + 1];
        float z = coord[3 * i + 2];
        sx[i] = x; sy[i] = y; sz[i] = z;
        sn[i] = __fadd_rn(__fadd_rn(__fmul_rn(x, x), __fmul_rn(y, y)), __fmul_rn(z, z));
        int ix = (int)(x * 16.0f); ix = ix < 0 ? 0 : (ix > 15 ? 15 : ix);
        int iy = (int)(y * 16.0f); iy = iy < 0 ? 0 : (iy > 15 ? 15 : iy);
        int iz = (int)(z * 16.0f); iz = iz < 0 ? 0 : (iz > 15 ? 15 : iz);
        unsigned mc = spread4(ix) | (spread4(iy) << 1) | (spread4(iz) << 2);
        cell[i] = (int)mc;
        rank[i] = atomicAdd(&hist[mc], 1);
    }
}

// K2: exclusive scan of 4096-bin histogram
__global__ __launch_bounds__(1024) void scan_kernel(const int* __restrict__ hist,
                                                    int* __restrict__ cellstart) {
    __shared__ int buf[1024];
    int t = threadIdx.x;
    int h0 = hist[4 * t], h1 = hist[4 * t + 1], h2 = hist[4 * t + 2], h3 = hist[4 * t + 3];
    int s = h0 + h1 + h2 + h3;
    buf[t] = s;
    __syncthreads();
    for (int off = 1; off < 1024; off <<= 1) {
        int v = (t >= off) ? buf[t - off] : 0;
        __syncthreads();
        buf[t] += v;
        __syncthreads();
    }
    int ex = buf[t] - s;
    cellstart[4 * t]     = ex;
    cellstart[4 * t + 1] = ex + h0;
    cellstart[4 * t + 2] = ex + h0 + h1;
    cellstart[4 * t + 3] = ex + h0 + h1 + h2;
}

// K3: scatter into Morton order (counting-sort pass 2)
__global__ void scatter_kernel(const float* __restrict__ sx, const float* __restrict__ sy,
                               const float* __restrict__ sz,
                               const int* __restrict__ cell, const int* __restrict__ rank,
                               const int* __restrict__ cellstart, int N,
                               float* __restrict__ rx, float* __restrict__ ry,
                               float* __restrict__ rz, int* __restrict__ rorig) {
    int i = blockIdx.x * blockDim.x + threadIdx.x;
    if (i < N) {
        int pos = cellstart[cell[i]] + rank[i];
        rx[pos] = sx[i]; ry[pos] = sy[i]; rz[pos] = sz[i];
        rorig[pos] = i;
    }
}

// K3b: pad [N, FCAP) with sentinels so fps can do branchless float4 loads
__global__ void pad_kernel(float* __restrict__ rx, float* __restrict__ ry,
                           float* __restrict__ rz, int* __restrict__ rorig,
                           int N, int cap) {
    int i = N + blockIdx.x * blockDim.x + threadIdx.x;
    if (i < cap) { rx[i] = 1e18f; ry[i] = 1e18f; rz[i] = 1e18f; rorig[i] = 0x7fffffff; }
}

// K4: FPS. Registers hold ONLY md[]; coords + orig-idx re-read from L1 as float4/int4.
// Spatial prune: thread skips its whole update when (D - r_t)^2 > max md (conservative).
// Single barrier per step; slim LDS reduce: int2 (v,i) per wave + float4 winner coords.
#define INIT_PT(j, PX, PY, PZ, OI)                                                       \
    {                                                                                    \
        bool real = (base + (j) < N);                                                    \
        float d = sq_dist_nofma((PX), (PY), (PZ), c0x, c0y, c0z);                        \
        float m = real ? d : -3e38f;                                                     \
        md[j] = m;                                                                       \
        if (m > bv || (m == bv && (OI) < bi)) {                                          \
            bv = m; bi = (OI); bx = (PX); by = (PY); bz = (PZ);                          \
        }                                                                                \
        if (real) {                                                                      \
            mnx = fminf(mnx, (PX)); mxx = fmaxf(mxx, (PX));                              \
            mny = fminf(mny, (PY)); mxy = fmaxf(mxy, (PY));                              \
            mnz = fminf(mnz, (PZ)); mxz = fmaxf(mxz, (PZ));                              \
        }                                                                                \
    }

#define UPD_PT(j, PX, PY, PZ, OI)                                                        \
    {                                                                                    \
        float d = sq_dist_nofma((PX), (PY), (PZ), ncx, ncy, ncz);                        \
        float m = fminf(md[j], d);                                                       \
        md[j] = m;                                                                       \
        if (m > bv || (m == bv && (OI) < bi)) {                                          \
            bv = m; bi = (OI); bx = (PX); by = (PY); bz = (PZ);                          \
        }                                                                                \
    }

__global__ __launch_bounds__(FT, 2)
void fps_kernel(const float* __restrict__ rx, const float* __restrict__ ry,
                const float* __restrict__ rz, const int* __restrict__ rorig,
                const float* __restrict__ sx, const float* __restrict__ sy,
                const float* __restrict__ sz,
                int N, int n_dst, int* __restrict__ out_idx) {
    __shared__ int2   vi[2][NW];    // [parity][wave] = (v bits, orig idx)
    __shared__ float4 xyz[2][NW];   // [parity][wave] = winner coords

    const int tid  = threadIdx.x;
    const int wv   = tid >> 6;
    const int base = tid * FP;
    int npts = N - base; npts = npts < 0 ? 0 : (npts > FP ? FP : npts);

    const float4* rx4 = (const float4*)rx + tid * FPQ;
    const float4* ry4 = (const float4*)ry + tid * FPQ;
    const float4* rz4 = (const float4*)rz + tid * FPQ;
    const int4*   ro4 = (const int4*)rorig + tid * FPQ;

    float md[FP];

    const float c0x = sx[0], c0y = sy[0], c0z = sz[0];
    float mnx = 1e30f, mny = 1e30f, mnz = 1e30f, mxx = -1e30f, mxy = -1e30f, mxz = -1e30f;
    float bv = -3e38f, bx = 0.f, by = 0.f, bz = 0.f; int bi = 0x7fffffff;

    #pragma unroll
    for (int q = 0; q < FPQ; ++q) {
        float4 X = rx4[q], Y = ry4[q], Z = rz4[q];
        int4   I = ro4[q];
        INIT_PT(4 * q + 0, X.x, Y.x, Z.x, I.x);
        INIT_PT(4 * q + 1, X.y, Y.y, Z.y, I.y);
        INIT_PT(4 * q + 2, X.z, Y.z, Z.z, I.z);
        INIT_PT(4 * q + 3, X.w, Y.w, Z.w, I.w);
    }

    // bounding sphere (conservative)
    float ctx = 0.5f * (mnx + mxx), cty = 0.5f * (mny + mxy), ctz = 0.5f * (mnz + mxz);
    float rt = 0.f;
    if (npts > 0) {
        float ex = fmaxf(mxx - ctx, ctx - mnx);
        float ey = fmaxf(mxy - cty, cty - mny);
        float ez = fmaxf(mxz - ctz, ctz - mnz);
        rt = sqrtf(ex * ex + ey * ey + ez * ez) * 1.0001f + 1e-7f;
    }
    float thr2 = -1.f;
    if (npts > 0) { float t0 = sqrtf(fmaxf(bv, 0.f)) * 1.0001f + rt; thr2 = t0 * t0 * 1.0002f + 1e-12f; }
    if (tid == 0) out_idx[0] = 0;

    int par = 0;
    for (int s = 1; s < n_dst; ++s) {
        // wave argmax of (bv, bi), first-original-index tie-break
        float v = bv; int i = bi;
        #pragma unroll
        for (int off = 32; off; off >>= 1) {
            float v2 = __shfl_xor(v, off, 64);
            int   i2 = __shfl_xor(i, off, 64);
            if (v2 > v || (v2 == v && i2 < i)) { v = v2; i = i2; }
        }
        if (bi == i) {   // owner lane (unique: real orig indices are unique; no all-empty wave)
            vi[par][wv]  = make_int2(__float_as_int(v), i);
            xyz[par][wv] = make_float4(bx, by, bz, 0.f);
        }
        __syncthreads();
        float Wv = -3e38f; int Wi = 0x7fffffff; int Ww = 0;
        #pragma unroll
        for (int w = 0; w < NW; ++w) {
            int2 t = vi[par][w];
            float tv = __int_as_float(t.x);
            if (tv > Wv || (tv == Wv && t.y < Wi)) { Wv = tv; Wi = t.y; Ww = w; }
        }
        float4 wc = xyz[par][Ww];
        float ncx = wc.x, ncy = wc.y, ncz = wc.z;
        if (tid == 0) out_idx[s] = Wi;
        par ^= 1;   // double-buffered tuples: no second barrier needed

        // spatial prune: skip whole thread when no md can decrease (thr2=-1 for empty threads)
        float Dx = ncx - ctx, Dy = ncy - cty, Dz = ncz - ctz;
        float D2 = Dx * Dx + Dy * Dy + Dz * Dz;
        if (D2 <= thr2) {
            bv = -3e38f; bi = 0x7fffffff;
            #pragma unroll
            for (int q = 0; q < FPQ; ++q) {
                float4 X = rx4[q], Y = ry4[q], Z = rz4[q];
                int4   I = ro4[q];
                UPD_PT(4 * q + 0, X.x, Y.x, Z.x, I.x);
                UPD_PT(4 * q + 1, X.y, Y.y, Z.y, I.y);
                UPD_PT(4 * q + 2, X.z, Y.z, Z.z, I.z);
                UPD_PT(4 * q + 3, X.w, Y.w, Z.w, I.w);
            }
            float t0 = sqrtf(fmaxf(bv, 0.f)) * 1.0001f + rt;
            thr2 = t0 * t0 * 1.0002f + 1e-12f;
        }
        // pruned threads keep valid (bv, bi, bx, by, bz, thr2): md provably unchanged
    }
}

// K5: ball query, one wave per dst. First K in-radius src indices in ascending order.
__global__ void ball_kernel(const float* __restrict__ sx, const float* __restrict__ sy,
                            const float* __restrict__ sz, const float* __restrict__ sn,
                            const int* __restrict__ idx,
                            const float* __restrict__ coord, const int* __restrict__ batch,
                            int N, int n_dst,
                            float* __restrict__ out_coord, float* __restrict__ out_esrc,
                            float* __restrict__ out_edst, float* __restrict__ out_deg,
                            float* __restrict__ out_batch,
                            int* __restrict__ nbr_i, int* __restrict__ deg_i) {
    const int d    = blockIdx.x;
    const int lane = threadIdx.x;   // block of 64
    __shared__ int nbr[KNBR];

    const int id = idx[d];
    const float cx = sx[id], cy = sy[id], cz = sz[id];
    const float dn = sn[id];
    const float RR = (float)(0.08 * 0.08);

    int cnt = 0;
    for (int base = 0; base < N && cnt < KNBR; base += 64) {
        int i = base + lane;
        bool in = false;
        if (i < N) {
            float t     = __fmul_rn(sx[i], cx);
            float inner = __fmaf_rn(sy[i], cy, t);
            inner       = __fmaf_rn(sz[i], cz, inner);
            float d2    = __fsub_rn(__fadd_rn(dn, sn[i]), __fmul_rn(2.0f, inner));
            in = (d2 <= RR);
        }
        unsigned long long m = __ballot(in);
        int pos = cnt + __popcll(m & ((1ull << lane) - 1ull));
        if (in && pos < KNBR) nbr[pos] = i;
        cnt += (int)__popcll(m);
    }
    __syncthreads();

    int deg = cnt < KNBR ? cnt : KNBR;
    if (lane < KNBR) {
        int e = (lane < deg) ? nbr[lane] : -1;
        out_esrc[d * KNBR + lane] = (float)e;
        out_edst[d * KNBR + lane] = (float)((lane < deg) ? d : -1);
        nbr_i[d * KNBR + lane] = e;
    }
    if (lane == 0) { out_deg[d] = (float)deg; deg_i[d] = deg; }
    if (lane < 3)  out_coord[d * 3 + lane] = coord[id * 3 + lane];
    if (lane == 3) out_batch[d] = (float)batch[id];
}

// K6: scatter-mean of gathered features. One block per dst, one thread per feature dim.
__global__ void agg_kernel(const float* __restrict__ feat,
                           const int* __restrict__ nbr_i, const int* __restrict__ deg_i,
                           int F, float* __restrict__ out_feat) {
    const int d = blockIdx.x;
    const int t = threadIdx.x;  // F threads
    const int deg = deg_i[d];
    float acc = 0.0f;
    for (int k = 0; k < deg; ++k) {
        int nb = nbr_i[d * KNBR + k];
        acc = __fadd_rn(acc, feat[nb * F + t]);
    }
    float den = (float)(deg > 0 ? deg : 1);
    out_feat[d * F + t] = acc / den;
}

extern "C" void kernel_launch(void* const* d_in, const int* in_sizes, int n_in,
                              void* d_out, int out_size, void* d_ws, size_t ws_size,
                              hipStream_t stream) {
    const float* coord = (const float*)d_in[0];
    const float* feat  = (const float*)d_in[1];
    const int*   batch = (const int*)d_in[2];

    const int N     = in_sizes[0] / 3;
    const int F     = in_sizes[1] / N;
    const int n_dst = N / 4;            // RATIO = 0.25

    // workspace layout (rx 16B-aligned: 4N floats precede it, N=20000 -> 320000 B)
    float* sx = (float*)d_ws;
    float* sy = sx + N;
    float* sz = sy + N;
    float* sn = sz + N;
    float* rx = sn + N;
    float* ry = rx + FCAP;
    float* rz = ry + FCAP;
    int*   rorig     = (int*)(rz + FCAP);
    int*   cell      = rorig + FCAP;
    int*   rank      = cell + N;
    int*   hist      = rank + N;
    int*   cellstart = hist + NCELL;
    int*   idx       = cellstart + NCELL;
    int*   nbr_i     = idx + n_dst;
    int*   deg_i     = nbr_i + n_dst * KNBR;

    // output layout (all float32), reference return order
    float* out     = (float*)d_out;
    float* o_coord = out;                         // n_dst*3
    float* o_feat  = o_coord + (size_t)n_dst * 3; // n_dst*F
    float* o_esrc  = o_feat  + (size_t)n_dst * F; // n_dst*K
    float* o_edst  = o_esrc  + (size_t)n_dst * KNBR;
    float* o_deg   = o_edst  + (size_t)n_dst * KNBR;
    float* o_batch = o_deg   + n_dst;

    hipMemsetAsync(hist, 0, NCELL * sizeof(int), stream);
    prep_kernel<<<(N + 255) / 256, 256, 0, stream>>>(coord, N, sx, sy, sz, sn,
                                                     cell, rank, hist);
    scan_kernel<<<1, 1024, 0, stream>>>(hist, cellstart);
    scatter_kernel<<<(N + 255) / 256, 256, 0, stream>>>(sx, sy, sz, cell, rank,
                                                        cellstart, N, rx, ry, rz, rorig);
    pad_kernel<<<(FCAP - N + 255) / 256, 256, 0, stream>>>(rx, ry, rz, rorig, N, FCAP);
    fps_kernel<<<1, FT, 0, stream>>>(rx, ry, rz, rorig, sx, sy, sz, N, n_dst, idx);
    ball_kernel<<<n_dst, 64, 0, stream>>>(sx, sy, sz, sn, idx, coord, batch, N, n_dst,
                                          o_coord, o_esrc, o_edst, o_deg, o_batch,
                                          nbr_i, deg_i);
    agg_kernel<<<n_dst, F, 0, stream>>>(feat, nbr_i, deg_i, F, o_feat);
}

// Round 6
// 21850.775 us; speedup vs baseline: 1.3141x; 1.3141x over previous
//
#include <hip/hip_runtime.h>

#define KNBR 32
#define NCELL 4096      // 16^3 Morton cells
#define FT 1024         // fps threads (16 waves)
#define FP 20           // points per fps thread
#define FPQ (FP / 4)    // float4 md groups per thread
#define FCAP (FT * FP)  // padded capacity (20480)
#define NW (FT / 64)

// Reference-matching squared distance: ((dx*dx + dy*dy) + dz*dz), no FMA contraction.
__device__ __forceinline__ float sq_dist_nofma(float px, float py, float pz,
                                               float cx, float cy, float cz) {
    float dx = __fsub_rn(px, cx);
    float dy = __fsub_rn(py, cy);
    float dz = __fsub_rn(pz, cz);
    return __fadd_rn(__fadd_rn(__fmul_rn(dx, dx), __fmul_rn(dy, dy)), __fmul_rn(dz, dz));
}

__device__ __forceinline__ unsigned spread4(unsigned v) {
    return (v & 1u) | ((v & 2u) << 2) | ((v & 4u) << 4) | ((v & 8u) << 6);
}

// K1: AoS -> SoA + norms + Morton cell id + within-cell rank (counting-sort pass 1)
__global__ void prep_kernel(const float* __restrict__ coord, int N,
                            float* __restrict__ sx, float* __restrict__ sy,
                            float* __restrict__ sz, float* __restrict__ sn,
                            int* __restrict__ cell, int* __restrict__ rank,
                            int* __restrict__ hist) {
    int i = blockIdx.x * blockDim.x + threadIdx.x;
    if (i < N) {
        float x = coord[3 * i + 0];
        float y = coord[3 * i + 1];
        float z = coord[3 * i + 2];
        sx[i] = x; sy[i] = y; sz[i] = z;
        sn[i] = __fadd_rn(__fadd_rn(__fmul_rn(x, x), __fmul_rn(y, y)), __fmul_rn(z, z));
        int ix = (int)(x * 16.0f); ix = ix < 0 ? 0 : (ix > 15 ? 15 : ix);
        int iy = (int)(y * 16.0f); iy = iy < 0 ? 0 : (iy > 15 ? 15 : iy);
        int iz = (int)(z * 16.0f); iz = iz < 0 ? 0 : (iz > 15 ? 15 : iz);
        unsigned mc = spread4(ix) | (spread4(iy) << 1) | (spread4(iz) << 2);
        cell[i] = (int)mc;
        rank[i] = atomicAdd(&hist[mc], 1);
    }
}

// K2: exclusive scan of 4096-bin histogram
__global__ __launch_bounds__(1024) void scan_kernel(const int* __restrict__ hist,
                                                    int* __restrict__ cellstart) {
    __shared__ int buf[1024];
    int t = threadIdx.x;
    int h0 = hist[4 * t], h1 = hist[4 * t + 1], h2 = hist[4 * t + 2], h3 = hist[4 * t + 3];
    int s = h0 + h1 + h2 + h3;
    buf[t] = s;
    __syncthreads();
    for (int off = 1; off < 1024; off <<= 1) {
        int v = (t >= off) ? buf[t - off] : 0;
        __syncthreads();
        buf[t] += v;
        __syncthreads();
    }
    int ex = buf[t] - s;
    cellstart[4 * t]     = ex;
    cellstart[4 * t + 1] = ex + h0;
    cellstart[4 * t + 2] = ex + h0 + h1;
    cellstart[4 * t + 3] = ex + h0 + h1 + h2;
}

// K3: scatter into Morton order, packed as (x, y, z, orig_idx_bits)
__global__ void scatter_kernel(const float* __restrict__ sx, const float* __restrict__ sy,
                               const float* __restrict__ sz,
                               const int* __restrict__ cell, const int* __restrict__ rank,
                               const int* __restrict__ cellstart, int N,
                               float4* __restrict__ pts) {
    int i = blockIdx.x * blockDim.x + threadIdx.x;
    if (i < N) {
        int pos = cellstart[cell[i]] + rank[i];
        pts[pos] = make_float4(sx[i], sy[i], sz[i], __int_as_float(i));
    }
}

// K3b: sentinel padding
__global__ void pad_kernel(float4* __restrict__ pts, int N, int cap) {
    int i = N + blockIdx.x * blockDim.x + threadIdx.x;
    if (i < cap) pts[i] = make_float4(1e18f, 1e18f, 1e18f, __int_as_float(0x7fffffff));
}

// K4: FPS. NO per-thread arrays (the 5-round lesson: they always spill).
// md lives in a global float4 buffer (hot in L2, per-thread exclusive).
// Two-level conservative spatial prune: wave-level sphere (uniform branch, skips the
// whole loop) + lane-level sphere (masks loads). Single barrier per step.
#define UPD(MREF, P)                                                                     \
    {                                                                                    \
        float d = sq_dist_nofma((P).x, (P).y, (P).z, ncx, ncy, ncz);                     \
        float m = fminf((MREF), d);                                                      \
        (MREF) = m;                                                                      \
        int oi = __float_as_int((P).w);                                                  \
        if (m > bv || (m == bv && oi < bi)) {                                            \
            bv = m; bi = oi; bx = (P).x; by = (P).y; bz = (P).z;                         \
        }                                                                                \
    }

#define INITP(MREF, P, J)                                                                \
    {                                                                                    \
        int oi = __float_as_int((P).w);                                                  \
        bool real = (J) < npts;                                                          \
        float d = sq_dist_nofma((P).x, (P).y, (P).z, c0x, c0y, c0z);                     \
        float m = real ? d : -3e38f;                                                     \
        (MREF) = m;                                                                      \
        if (m > bv || (m == bv && oi < bi)) {                                            \
            bv = m; bi = oi; bx = (P).x; by = (P).y; bz = (P).z;                         \
        }                                                                                \
        if (real) {                                                                      \
            mnx = fminf(mnx, (P).x); mxx = fmaxf(mxx, (P).x);                            \
            mny = fminf(mny, (P).y); mxy = fmaxf(mxy, (P).y);                            \
            mnz = fminf(mnz, (P).z); mxz = fmaxf(mxz, (P).z);                            \
        }                                                                                \
    }

__global__ __launch_bounds__(FT)
void fps_kernel(const float4* __restrict__ pts, float4* __restrict__ mdg,
                const float* __restrict__ sx, const float* __restrict__ sy,
                const float* __restrict__ sz,
                int N, int n_dst, int* __restrict__ out_idx) {
    __shared__ int2   vi[2][NW];
    __shared__ float4 xyz[2][NW];

    const int tid  = threadIdx.x;
    const int wv   = tid >> 6;
    const int base = tid * FP;
    int npts = N - base; npts = npts < 0 ? 0 : (npts > FP ? FP : npts);

    const float4* my   = pts + base;       // 20 packed points
    float4*       mymd = mdg + tid * FPQ;  // 5 float4 md groups

    const float c0x = sx[0], c0y = sy[0], c0z = sz[0];
    float mnx = 1e30f, mny = 1e30f, mnz = 1e30f, mxx = -1e30f, mxy = -1e30f, mxz = -1e30f;
    float bv = -3e38f, bx = 0.f, by = 0.f, bz = 0.f; int bi = 0x7fffffff;

    #pragma unroll
    for (int q = 0; q < FPQ; ++q) {
        float4 P0 = my[4 * q + 0], P1 = my[4 * q + 1], P2 = my[4 * q + 2], P3 = my[4 * q + 3];
        float4 m4;
        INITP(m4.x, P0, 4 * q + 0);
        INITP(m4.y, P1, 4 * q + 1);
        INITP(m4.z, P2, 4 * q + 2);
        INITP(m4.w, P3, 4 * q + 3);
        mymd[q] = m4;
    }

    // lane bounding sphere (box half-diagonal bound, conservative)
    float ctx = 0.5f * (mnx + mxx), cty = 0.5f * (mny + mxy), ctz = 0.5f * (mnz + mxz);
    float rt = 0.f, thr2 = -1.f;
    if (npts > 0) {
        float ex = (mxx - mnx) * 0.5f, ey = (mxy - mny) * 0.5f, ez = (mxz - mnz) * 0.5f;
        rt = sqrtf(ex * ex + ey * ey + ez * ez) * 1.0001f + 1e-7f;
        float t0 = sqrtf(fmaxf(bv, 0.f)) * 1.0001f + rt;
        thr2 = t0 * t0 * 1.0002f + 1e-12f;
    }

    // wave bounding sphere via butterfly min/max (all lanes converge to same values)
    float wmnx = mnx, wmny = mny, wmnz = mnz, wmxx = mxx, wmxy = mxy, wmxz = mxz;
    #pragma unroll
    for (int off = 32; off; off >>= 1) {
        wmnx = fminf(wmnx, __shfl_xor(wmnx, off, 64));
        wmny = fminf(wmny, __shfl_xor(wmny, off, 64));
        wmnz = fminf(wmnz, __shfl_xor(wmnz, off, 64));
        wmxx = fmaxf(wmxx, __shfl_xor(wmxx, off, 64));
        wmxy = fmaxf(wmxy, __shfl_xor(wmxy, off, 64));
        wmxz = fmaxf(wmxz, __shfl_xor(wmxz, off, 64));
    }
    float wcx = 0.5f * (wmnx + wmxx), wcy = 0.5f * (wmny + wmxy), wcz = 0.5f * (wmnz + wmxz);
    float wex = (wmxx - wmnx) * 0.5f, wey = (wmxy - wmny) * 0.5f, wez = (wmxz - wmnz) * 0.5f;
    float wrt = sqrtf(wex * wex + wey * wey + wez * wez) * 1.0001f + 1e-7f;

    if (tid == 0) out_idx[0] = 0;

    int par = 0;
    for (int s = 1; s < n_dst; ++s) {
        // wave argmax of (bv, bi), first-original-index tie-break; v = wave max md
        float v = bv; int i = bi;
        #pragma unroll
        for (int off = 32; off; off >>= 1) {
            float v2 = __shfl_xor(v, off, 64);
            int   i2 = __shfl_xor(i, off, 64);
            if (v2 > v || (v2 == v && i2 < i)) { v = v2; i = i2; }
        }
        if (bi == i) {   // owner lane writes wave tuple (winner coords included)
            vi[par][wv]  = make_int2(__float_as_int(v), i);
            xyz[par][wv] = make_float4(bx, by, bz, 0.f);
        }
        __syncthreads();
        float Wv = -3e38f; int Wi = 0x7fffffff; int Ww = 0;
        #pragma unroll
        for (int w = 0; w < NW; ++w) {
            int2 t = vi[par][w];
            float tv = __int_as_float(t.x);
            if (tv > Wv || (tv == Wv && t.y < Wi)) { Wv = tv; Wi = t.y; Ww = w; }
        }
        float4 wcd = xyz[par][Ww];
        float ncx = wcd.x, ncy = wcd.y, ncz = wcd.z;
        if (tid == 0) out_idx[s] = Wi;
        par ^= 1;   // double-buffered tuples: no second barrier needed

        // wave-level prune (wave-uniform: v, wc, wrt identical across lanes)
        float wt = sqrtf(fmaxf(v, 0.f)) * 1.0001f + wrt;
        float wthr2 = wt * wt * 1.0002f + 1e-12f;
        float Dwx = ncx - wcx, Dwy = ncy - wcy, Dwz = ncz - wcz;
        if (Dwx * Dwx + Dwy * Dwy + Dwz * Dwz <= wthr2) {
            // lane-level prune
            float Dx = ncx - ctx, Dy = ncy - cty, Dz = ncz - ctz;
            if (Dx * Dx + Dy * Dy + Dz * Dz <= thr2) {
                bv = -3e38f; bi = 0x7fffffff;
                #pragma unroll
                for (int q = 0; q < FPQ; ++q) {
                    float4 P0 = my[4 * q + 0], P1 = my[4 * q + 1];
                    float4 P2 = my[4 * q + 2], P3 = my[4 * q + 3];
                    float4 m4 = mymd[q];
                    UPD(m4.x, P0);
                    UPD(m4.y, P1);
                    UPD(m4.z, P2);
                    UPD(m4.w, P3);
                    mymd[q] = m4;
                }
                float t0 = sqrtf(fmaxf(bv, 0.f)) * 1.0001f + rt;
                thr2 = t0 * t0 * 1.0002f + 1e-12f;
            }
        }
        // pruned lanes/waves keep valid (bv, bi, bx, by, bz, thr2): md provably unchanged
    }
}

// K5: ball query, one wave per dst. First K in-radius src indices in ascending order.
__global__ void ball_kernel(const float* __restrict__ sx, const float* __restrict__ sy,
                            const float* __restrict__ sz, const float* __restrict__ sn,
                            const int* __restrict__ idx,
                            const float* __restrict__ coord, const int* __restrict__ batch,
                            int N, int n_dst,
                            float* __restrict__ out_coord, float* __restrict__ out_esrc,
                            float* __restrict__ out_edst, float* __restrict__ out_deg,
                            float* __restrict__ out_batch,
                            int* __restrict__ nbr_i, int* __restrict__ deg_i) {
    const int d    = blockIdx.x;
    const int lane = threadIdx.x;   // block of 64
    __shared__ int nbr[KNBR];

    const int id = idx[d];
    const float cx = sx[id], cy = sy[id], cz = sz[id];
    const float dn = sn[id];
    const float RR = (float)(0.08 * 0.08);

    int cnt = 0;
    for (int base = 0; base < N && cnt < KNBR; base += 64) {
        int i = base + lane;
        bool in = false;
        if (i < N) {
            float t     = __fmul_rn(sx[i], cx);
            float inner = __fmaf_rn(sy[i], cy, t);
            inner       = __fmaf_rn(sz[i], cz, inner);
            float d2    = __fsub_rn(__fadd_rn(dn, sn[i]), __fmul_rn(2.0f, inner));
            in = (d2 <= RR);
        }
        unsigned long long m = __ballot(in);
        int pos = cnt + __popcll(m & ((1ull << lane) - 1ull));
        if (in && pos < KNBR) nbr[pos] = i;
        cnt += (int)__popcll(m);
    }
    __syncthreads();

    int deg = cnt < KNBR ? cnt : KNBR;
    if (lane < KNBR) {
        int e = (lane < deg) ? nbr[lane] : -1;
        out_esrc[d * KNBR + lane] = (float)e;
        out_edst[d * KNBR + lane] = (float)((lane < deg) ? d : -1);
        nbr_i[d * KNBR + lane] = e;
    }
    if (lane == 0) { out_deg[d] = (float)deg; deg_i[d] = deg; }
    if (lane < 3)  out_coord[d * 3 + lane] = coord[id * 3 + lane];
    if (lane == 3) out_batch[d] = (float)batch[id];
}

// K6: scatter-mean of gathered features. One block per dst, one thread per feature dim.
__global__ void agg_kernel(const float* __restrict__ feat,
                           const int* __restrict__ nbr_i, const int* __restrict__ deg_i,
                           int F, float* __restrict__ out_feat) {
    const int d = blockIdx.x;
    const int t = threadIdx.x;  // F threads
    const int deg = deg_i[d];
    float acc = 0.0f;
    for (int k = 0; k < deg; ++k) {
        int nb = nbr_i[d * KNBR + k];
        acc = __fadd_rn(acc, feat[nb * F + t]);
    }
    float den = (float)(deg > 0 ? deg : 1);
    out_feat[d * F + t] = acc / den;
}

extern "C" void kernel_launch(void* const* d_in, const int* in_sizes, int n_in,
                              void* d_out, int out_size, void* d_ws, size_t ws_size,
                              hipStream_t stream) {
    const float* coord = (const float*)d_in[0];
    const float* feat  = (const float*)d_in[1];
    const int*   batch = (const int*)d_in[2];

    const int N     = in_sizes[0] / 3;
    const int F     = in_sizes[1] / N;
    const int n_dst = N / 4;            // RATIO = 0.25

    // workspace layout (pts/md 16B-aligned: 4N floats precede pts, N=20000 -> 320000 B)
    float*  sx  = (float*)d_ws;
    float*  sy  = sx + N;
    float*  sz  = sy + N;
    float*  sn  = sz + N;
    float4* pts = (float4*)(sn + N);          // FCAP packed points
    float4* mdg = pts + FCAP;                 // FT*FPQ float4 md groups (= FCAP floats)
    int*    cell      = (int*)(mdg + FT * FPQ);
    int*    rank      = cell + N;
    int*    hist      = rank + N;
    int*    cellstart = hist + NCELL;
    int*    idx       = cellstart + NCELL;
    int*    nbr_i     = idx + n_dst;
    int*    deg_i     = nbr_i + n_dst * KNBR;

    // output layout (all float32), reference return order
    float* out     = (float*)d_out;
    float* o_coord = out;                         // n_dst*3
    float* o_feat  = o_coord + (size_t)n_dst * 3; // n_dst*F
    float* o_esrc  = o_feat  + (size_t)n_dst * F; // n_dst*K
    float* o_edst  = o_esrc  + (size_t)n_dst * KNBR;
    float* o_deg   = o_edst  + (size_t)n_dst * KNBR;
    float* o_batch = o_deg   + n_dst;

    hipMemsetAsync(hist, 0, NCELL * sizeof(int), stream);
    prep_kernel<<<(N + 255) / 256, 256, 0, stream>>>(coord, N, sx, sy, sz, sn,
                                                     cell, rank, hist);
    scan_kernel<<<1, 1024, 0, stream>>>(hist, cellstart);
    scatter_kernel<<<(N + 255) / 256, 256, 0, stream>>>(sx, sy, sz, cell, rank,
                                                        cellstart, N, pts);
    pad_kernel<<<(FCAP - N + 255) / 256, 256, 0, stream>>>(pts, N, FCAP);
    fps_kernel<<<1, FT, 0, stream>>>(pts, mdg, sx, sy, sz, N, n_dst, idx);
    ball_kernel<<<n_dst, 64, 0, stream>>>(sx, sy, sz, sn, idx, coord, batch, N, n_dst,
                                          o_coord, o_esrc, o_edst, o_deg, o_batch,
                                          nbr_i, deg_i);
    agg_kernel<<<n_dst, F, 0, stream>>>(feat, nbr_i, deg_i, F, o_feat);
}

// Round 7
// 12477.531 us; speedup vs baseline: 2.3013x; 1.7512x over previous
//
#include <hip/hip_runtime.h>

#define KNBR 32
#define NCELL 4096        // 16^3 Morton cells
#define MAXCHUNK 320      // ceil(20000/64)=313 <= 320
#define FCAP (MAXCHUNK * 64)
#define FT 512            // fps threads (8 waves)
#define NWAVE (FT / 64)

typedef unsigned long long u64;
typedef unsigned int u32;

// Reference-matching squared distance: ((dx*dx + dy*dy) + dz*dz), no FMA contraction.
__device__ __forceinline__ float sq_dist_nofma(float px, float py, float pz,
                                               float cx, float cy, float cz) {
    float dx = __fsub_rn(px, cx);
    float dy = __fsub_rn(py, cy);
    float dz = __fsub_rn(pz, cz);
    return __fadd_rn(__fadd_rn(__fmul_rn(dx, dx), __fmul_rn(dy, dy)), __fmul_rn(dz, dz));
}

__device__ __forceinline__ unsigned spread4(unsigned v) {
    return (v & 1u) | ((v & 2u) << 2) | ((v & 4u) << 4) | ((v & 8u) << 6);
}

// key = (md_bits << 32) | (0xFFFFFFFF - orig): uint64 max == (max md, then min orig).
// md >= 0 so float bits are monotone. Sentinels get key 0 (below any real key).
__device__ __forceinline__ u64 pack_key(float md, int orig) {
    return (orig != 0x7fffffff)
        ? (((u64)__float_as_uint(md) << 32) | (u64)(0xFFFFFFFFu - (u32)orig))
        : 0ull;
}

// K1: AoS -> SoA + norms + Morton cell id + within-cell rank (counting-sort pass 1)
__global__ void prep_kernel(const float* __restrict__ coord, int N,
                            float* __restrict__ sx, float* __restrict__ sy,
                            float* __restrict__ sz, float* __restrict__ sn,
                            int* __restrict__ cell, int* __restrict__ rank,
                            int* __restrict__ hist) {
    int i = blockIdx.x * blockDim.x + threadIdx.x;
    if (i < N) {
        float x = coord[3 * i + 0];
        float y = coord[3 * i + 1];
        float z = coord[3 * i + 2];
        sx[i] = x; sy[i] = y; sz[i] = z;
        sn[i] = __fadd_rn(__fadd_rn(__fmul_rn(x, x), __fmul_rn(y, y)), __fmul_rn(z, z));
        int ix = (int)(x * 16.0f); ix = ix < 0 ? 0 : (ix > 15 ? 15 : ix);
        int iy = (int)(y * 16.0f); iy = iy < 0 ? 0 : (iy > 15 ? 15 : iy);
        int iz = (int)(z * 16.0f); iz = iz < 0 ? 0 : (iz > 15 ? 15 : iz);
        unsigned mc = spread4(ix) | (spread4(iy) << 1) | (spread4(iz) << 2);
        cell[i] = (int)mc;
        rank[i] = atomicAdd(&hist[mc], 1);
    }
}

// K2: exclusive scan of 4096-bin histogram
__global__ __launch_bounds__(1024) void scan_kernel(const int* __restrict__ hist,
                                                    int* __restrict__ cellstart) {
    __shared__ int buf[1024];
    int t = threadIdx.x;
    int h0 = hist[4 * t], h1 = hist[4 * t + 1], h2 = hist[4 * t + 2], h3 = hist[4 * t + 3];
    int s = h0 + h1 + h2 + h3;
    buf[t] = s;
    __syncthreads();
    for (int off = 1; off < 1024; off <<= 1) {
        int v = (t >= off) ? buf[t - off] : 0;
        __syncthreads();
        buf[t] += v;
        __syncthreads();
    }
    int ex = buf[t] - s;
    cellstart[4 * t]     = ex;
    cellstart[4 * t + 1] = ex + h0;
    cellstart[4 * t + 2] = ex + h0 + h1;
    cellstart[4 * t + 3] = ex + h0 + h1 + h2;
}

// K3: scatter into Morton order, packed as (x, y, z, orig_idx_bits)
__global__ void scatter_kernel(const float* __restrict__ sx, const float* __restrict__ sy,
                               const float* __restrict__ sz,
                               const int* __restrict__ cell, const int* __restrict__ rank,
                               const int* __restrict__ cellstart, int N,
                               float4* __restrict__ pts) {
    int i = blockIdx.x * blockDim.x + threadIdx.x;
    if (i < N) {
        int pos = cellstart[cell[i]] + rank[i];
        pts[pos] = make_float4(sx[i], sy[i], sz[i], __int_as_float(i));
    }
}

// K3b: sentinel padding
__global__ void pad_kernel(float4* __restrict__ pts, int N, int cap) {
    int i = N + blockIdx.x * blockDim.x + threadIdx.x;
    if (i < cap) pts[i] = make_float4(1e18f, 1e18f, 1e18f, __int_as_float(0x7fffffff));
}

// K3c: per-chunk init — md vs original point 0, chunk bounding sphere, chunk key.
// One 64-thread block per chunk.
__global__ void init_chunk_kernel(const float4* __restrict__ pts,
                                  const float* __restrict__ coord,
                                  float* __restrict__ mdbuf,
                                  float4* __restrict__ spheres,
                                  u64* __restrict__ ckeys) {
    int c = blockIdx.x, lane = threadIdx.x;
    int pos = (c << 6) + lane;
    float4 P = pts[pos];
    int orig = __float_as_int(P.w);
    bool real = (orig != 0x7fffffff);
    float c0x = coord[0], c0y = coord[1], c0z = coord[2];
    float d = sq_dist_nofma(P.x, P.y, P.z, c0x, c0y, c0z);
    float m = real ? d : -3e38f;
    mdbuf[pos] = m;
    u64 key = pack_key(m, orig);
    float mnx = real ? P.x : 1e30f, mxx = real ? P.x : -1e30f;
    float mny = real ? P.y : 1e30f, mxy = real ? P.y : -1e30f;
    float mnz = real ? P.z : 1e30f, mxz = real ? P.z : -1e30f;
    #pragma unroll
    for (int off = 32; off; off >>= 1) {
        u64 k2 = __shfl_xor(key, off, 64);
        if (k2 > key) key = k2;
        mnx = fminf(mnx, __shfl_xor(mnx, off, 64));
        mxx = fmaxf(mxx, __shfl_xor(mxx, off, 64));
        mny = fminf(mny, __shfl_xor(mny, off, 64));
        mxy = fmaxf(mxy, __shfl_xor(mxy, off, 64));
        mnz = fminf(mnz, __shfl_xor(mnz, off, 64));
        mxz = fmaxf(mxz, __shfl_xor(mxz, off, 64));
    }
    if (lane == 0) {
        float cx = 0.5f * (mnx + mxx), cy = 0.5f * (mny + mxy), cz = 0.5f * (mnz + mxz);
        float ex = (mxx - mnx) * 0.5f, ey = (mxy - mny) * 0.5f, ez = (mxz - mnz) * 0.5f;
        float r = sqrtf(ex * ex + ey * ey + ez * ez) * 1.0001f + 1e-7f;
        spheres[c] = make_float4(cx, cy, cz, r);
        ckeys[c] = key;
    }
}

// K4: chunked FPS. ~25 live registers, NO per-thread arrays (the 6-round lesson).
// LDS: chunk spheres (static), chunk keys (md_max + tie-break), active-chunk queue.
// Per step: argmax over keys -> winner; conservative sphere prune -> queue; waves
// process queued chunks (64 lanes = 64 points, coalesced global md RMW).
__global__ __launch_bounds__(FT)
void fps_kernel(const float4* __restrict__ pts, float* __restrict__ mdbuf,
                const float4* __restrict__ spheres_g, const u64* __restrict__ ckeys_g,
                const float* __restrict__ coord,
                int nchunk, int n_dst, int* __restrict__ out_idx) {
    __shared__ float4 sph[MAXCHUNK];
    __shared__ u64    keys[MAXCHUNK];
    __shared__ int    queue[MAXCHUNK];
    __shared__ u64    wwin[NWAVE];
    __shared__ int    qcnt;

    const int tid = threadIdx.x, lane = tid & 63, wv = tid >> 6;

    for (int i = tid; i < MAXCHUNK; i += FT) {
        keys[i] = (i < nchunk) ? ckeys_g[i] : 0ull;
        if (i < nchunk) sph[i] = spheres_g[i];
    }
    if (tid == 0) { qcnt = 0; out_idx[0] = 0; }
    __syncthreads();

    for (int s = 1; s < n_dst; ++s) {
        // A: argmax over chunk keys (one key per thread; nchunk <= FT)
        u64 k = (tid < nchunk) ? keys[tid] : 0ull;
        #pragma unroll
        for (int off = 32; off; off >>= 1) {
            u64 k2 = __shfl_xor(k, off, 64);
            if (k2 > k) k = k2;
        }
        if (lane == 0) wwin[wv] = k;
        if (tid == 0) qcnt = 0;           // consumed last step (before B3)
        __syncthreads();                  // B1
        u64 kb = wwin[0];
        #pragma unroll
        for (int w = 1; w < NWAVE; ++w) { u64 t = wwin[w]; if (t > kb) kb = t; }
        int orig = (int)(0xFFFFFFFFu - (u32)(kb & 0xFFFFFFFFull));
        float ncx = coord[3 * orig], ncy = coord[3 * orig + 1], ncz = coord[3 * orig + 2];
        if (tid == 0) out_idx[s] = orig;

        // B: conservative sphere prune -> active-chunk queue.
        // Pruned chunk c: for all p in c, d(p,nc) >= D - r > sqrt(maxmd) => no md change.
        // Winner's own chunk is never pruned (center lies inside its sphere).
        if (tid < nchunk) {
            float4 S = sph[tid];
            float maxmd = __uint_as_float((u32)(keys[tid] >> 32));
            float Dx = ncx - S.x, Dy = ncy - S.y, Dz = ncz - S.z;
            float D2 = Dx * Dx + Dy * Dy + Dz * Dz;
            float t0 = sqrtf(maxmd) * 1.0001f + S.w;
            float thr = t0 * t0 * 1.0002f + 1e-12f;
            if (D2 <= thr) queue[atomicAdd(&qcnt, 1)] = tid;
        }
        __syncthreads();                  // B2

        // C: waves process active chunks (64 lanes = 64 points each)
        int qn = qcnt;
        for (int j = wv; j < qn; j += NWAVE) {
            int c = queue[j];
            int pos = (c << 6) + lane;
            float4 P = pts[pos];
            float m = mdbuf[pos];
            float d = sq_dist_nofma(P.x, P.y, P.z, ncx, ncy, ncz);
            float m2 = fminf(m, d);
            mdbuf[pos] = m2;
            u64 kk = pack_key(m2, __float_as_int(P.w));
            #pragma unroll
            for (int off = 32; off; off >>= 1) {
                u64 k2 = __shfl_xor(kk, off, 64);
                if (k2 > kk) kk = k2;
            }
            if (lane == 0) keys[c] = kk;
        }
        __syncthreads();                  // B3
    }
}

// K5: ball query, one wave per dst. First K in-radius src indices in ascending order.
__global__ void ball_kernel(const float* __restrict__ sx, const float* __restrict__ sy,
                            const float* __restrict__ sz, const float* __restrict__ sn,
                            const int* __restrict__ idx,
                            const float* __restrict__ coord, const int* __restrict__ batch,
                            int N, int n_dst,
                            float* __restrict__ out_coord, float* __restrict__ out_esrc,
                            float* __restrict__ out_edst, float* __restrict__ out_deg,
                            float* __restrict__ out_batch,
                            int* __restrict__ nbr_i, int* __restrict__ deg_i) {
    const int d    = blockIdx.x;
    const int lane = threadIdx.x;   // block of 64
    __shared__ int nbr[KNBR];

    const int id = idx[d];
    const float cx = sx[id], cy = sy[id], cz = sz[id];
    const float dn = sn[id];
    const float RR = (float)(0.08 * 0.08);

    int cnt = 0;
    for (int base = 0; base < N && cnt < KNBR; base += 64) {
        int i = base + lane;
        bool in = false;
        if (i < N) {
            float t     = __fmul_rn(sx[i], cx);
            float inner = __fmaf_rn(sy[i], cy, t);
            inner       = __fmaf_rn(sz[i], cz, inner);
            float d2    = __fsub_rn(__fadd_rn(dn, sn[i]), __fmul_rn(2.0f, inner));
            in = (d2 <= RR);
        }
        unsigned long long m = __ballot(in);
        int pos = cnt + __popcll(m & ((1ull << lane) - 1ull));
        if (in && pos < KNBR) nbr[pos] = i;
        cnt += (int)__popcll(m);
    }
    __syncthreads();

    int deg = cnt < KNBR ? cnt : KNBR;
    if (lane < KNBR) {
        int e = (lane < deg) ? nbr[lane] : -1;
        out_esrc[d * KNBR + lane] = (float)e;
        out_edst[d * KNBR + lane] = (float)((lane < deg) ? d : -1);
        nbr_i[d * KNBR + lane] = e;
    }
    if (lane == 0) { out_deg[d] = (float)deg; deg_i[d] = deg; }
    if (lane < 3)  out_coord[d * 3 + lane] = coord[id * 3 + lane];
    if (lane == 3) out_batch[d] = (float)batch[id];
}

// K6: scatter-mean of gathered features. One block per dst, one thread per feature dim.
__global__ void agg_kernel(const float* __restrict__ feat,
                           const int* __restrict__ nbr_i, const int* __restrict__ deg_i,
                           int F, float* __restrict__ out_feat) {
    const int d = blockIdx.x;
    const int t = threadIdx.x;  // F threads
    const int deg = deg_i[d];
    float acc = 0.0f;
    for (int k = 0; k < deg; ++k) {
        int nb = nbr_i[d * KNBR + k];
        acc = __fadd_rn(acc, feat[nb * F + t]);
    }
    float den = (float)(deg > 0 ? deg : 1);
    out_feat[d * F + t] = acc / den;
}

extern "C" void kernel_launch(void* const* d_in, const int* in_sizes, int n_in,
                              void* d_out, int out_size, void* d_ws, size_t ws_size,
                              hipStream_t stream) {
    const float* coord = (const float*)d_in[0];
    const float* feat  = (const float*)d_in[1];
    const int*   batch = (const int*)d_in[2];

    const int N      = in_sizes[0] / 3;
    const int F      = in_sizes[1] / N;
    const int n_dst  = N / 4;                 // RATIO = 0.25
    const int nchunk = (N + 63) / 64;         // 313

    // workspace layout (pts 16B-aligned: 4N floats precede it; N=20000 -> 320000 B)
    float*  sx      = (float*)d_ws;
    float*  sy      = sx + N;
    float*  sz      = sy + N;
    float*  sn      = sz + N;
    float4* pts     = (float4*)(sn + N);      // FCAP packed points
    float4* spheres = pts + FCAP;             // MAXCHUNK
    float*  mdbuf   = (float*)(spheres + MAXCHUNK);   // FCAP floats
    u64*    ckeys   = (u64*)(mdbuf + FCAP);   // MAXCHUNK (8B-aligned: offset mult of 16)
    int*    cell      = (int*)(ckeys + MAXCHUNK);
    int*    rank      = cell + N;
    int*    hist      = rank + N;
    int*    cellstart = hist + NCELL;
    int*    idx       = cellstart + NCELL;
    int*    nbr_i     = idx + n_dst;
    int*    deg_i     = nbr_i + n_dst * KNBR;

    // output layout (all float32), reference return order
    float* out     = (float*)d_out;
    float* o_coord = out;                         // n_dst*3
    float* o_feat  = o_coord + (size_t)n_dst * 3; // n_dst*F
    float* o_esrc  = o_feat  + (size_t)n_dst * F; // n_dst*K
    float* o_edst  = o_esrc  + (size_t)n_dst * KNBR;
    float* o_deg   = o_edst  + (size_t)n_dst * KNBR;
    float* o_batch = o_deg   + n_dst;

    hipMemsetAsync(hist, 0, NCELL * sizeof(int), stream);
    prep_kernel<<<(N + 255) / 256, 256, 0, stream>>>(coord, N, sx, sy, sz, sn,
                                                     cell, rank, hist);
    scan_kernel<<<1, 1024, 0, stream>>>(hist, cellstart);
    scatter_kernel<<<(N + 255) / 256, 256, 0, stream>>>(sx, sy, sz, cell, rank,
                                                        cellstart, N, pts);
    pad_kernel<<<(nchunk * 64 - N + 255) / 256, 256, 0, stream>>>(pts, N, nchunk * 64);
    init_chunk_kernel<<<nchunk, 64, 0, stream>>>(pts, coord, mdbuf, spheres, ckeys);
    fps_kernel<<<1, FT, 0, stream>>>(pts, mdbuf, spheres, ckeys, coord,
                                     nchunk, n_dst, idx);
    ball_kernel<<<n_dst, 64, 0, stream>>>(sx, sy, sz, sn, idx, coord, batch, N, n_dst,
                                          o_coord, o_esrc, o_edst, o_deg, o_batch,
                                          nbr_i, deg_i);
    agg_kernel<<<n_dst, F, 0, stream>>>(feat, nbr_i, deg_i, F, o_feat);
}